// Round 4
// baseline (3294.471 us; speedup 1.0000x reference)
//
#include <hip/hip_runtime.h>

#define N_NODES 100000
#define N_EDGES 1600000
#define NFEAT 128
#define NCLASS 40

// ---------------- degree / normalization ----------------

__global__ void deg_init(float* __restrict__ deg) {
    int i = blockIdx.x * blockDim.x + threadIdx.x;
    if (i < N_NODES) deg[i] = 1.0f;  // self-loop contributes 1
}

__global__ void deg_count(const int* __restrict__ col, float* __restrict__ deg) {
    int e = blockIdx.x * blockDim.x + threadIdx.x;
    if (e < N_EDGES) unsafeAtomicAdd(&deg[col[e]], 1.0f);
}

__global__ void deg_to_dis(float* __restrict__ deg) {
    int i = blockIdx.x * blockDim.x + threadIdx.x;
    if (i < N_NODES) deg[i] = rsqrtf(deg[i]);  // deg >= 1 always
}

// per-edge norm precompute, reused by 3 hops
__global__ void prep_edges(const int* __restrict__ row, const int* __restrict__ col,
                           const float* __restrict__ dis, float* __restrict__ nrm) {
    int e = blockIdx.x * blockDim.x + threadIdx.x;
    if (e >= N_EDGES) return;
    nrm[e] = dis[row[e]] * dis[col[e]];
}

// ---------------- projection first: Z = X @ W  (N x 128 @ 128 x 40) ----------------

__global__ void gemm_xw(const float* __restrict__ x, const float* __restrict__ W,
                        float* __restrict__ z) {
    __shared__ float Ws[NFEAT * NCLASS];
    for (int i = threadIdx.x; i < NFEAT * NCLASS; i += blockDim.x) Ws[i] = W[i];
    __syncthreads();
    int t = blockIdx.x * blockDim.x + threadIdx.x;
    if (t >= N_NODES * NCLASS) return;
    int n = t / NCLASS;
    int c = t - n * NCLASS;
    const float* xr = x + (size_t)n * NFEAT;
    float acc = 0.0f;
#pragma unroll 8
    for (int f = 0; f < NFEAT; ++f) acc += xr[f] * Ws[f * NCLASS + c];
    z[t] = acc;
}

// ---------------- propagation hop on 40-dim features ----------------

// zout[i] = dis[i]^2 * zin[i] (+ b)   -- self-loop term; float4 over 40 floats (10/node)
__global__ void hop_init(const float* __restrict__ zin, const float* __restrict__ dis,
                         const float* __restrict__ b, float* __restrict__ zout) {
    int t = blockIdx.x * blockDim.x + threadIdx.x;  // N_NODES * 10 float4 units
    if (t >= N_NODES * 10) return;
    int n = t / 10;
    int q = t - n * 10;
    float d = dis[n];
    float s = d * d;
    float4 v = reinterpret_cast<const float4*>(zin)[t];
    v.x *= s; v.y *= s; v.z *= s; v.w *= s;
    if (b != nullptr) {
        float4 bb = reinterpret_cast<const float4*>(b)[q];
        v.x += bb.x; v.y += bb.y; v.z += bb.z; v.w += bb.w;
    }
    reinterpret_cast<float4*>(zout)[t] = v;
}

// zout[col] += nrm * zin[row]; 10 threads per edge, float4 each (4 scalar atomics)
__global__ void hop_edges(const int* __restrict__ row, const int* __restrict__ col,
                          const float* __restrict__ nrm, const float* __restrict__ zin,
                          float* __restrict__ zout) {
    int t = blockIdx.x * blockDim.x + threadIdx.x;  // N_EDGES * 10 float4 units (16M)
    if (t >= N_EDGES * 10) return;
    int e = t / 10;
    int j = t - e * 10;
    int r = row[e];
    int c = col[e];
    float s = nrm[e];
    float4 v = reinterpret_cast<const float4*>(zin + (size_t)r * NCLASS)[j];
    float* dst = zout + (size_t)c * NCLASS + j * 4;
    unsafeAtomicAdd(dst + 0, s * v.x);
    unsafeAtomicAdd(dst + 1, s * v.y);
    unsafeAtomicAdd(dst + 2, s * v.z);
    unsafeAtomicAdd(dst + 3, s * v.w);
}

// ---------------- launch ----------------

extern "C" void kernel_launch(void* const* d_in, const int* in_sizes, int n_in,
                              void* d_out, int out_size, void* d_ws, size_t ws_size,
                              hipStream_t stream) {
    const float* x = (const float*)d_in[0];
    const int* ei = (const int*)d_in[1];  // harness uploads integer inputs as int32; [2, E]
    const float* W = (const float*)d_in[2];
    const float* b = (const float*)d_in[3];
    // d_in[4] = k (fixed at 3 by setup; hardcoded — no host readback under graph capture)

    const int* row = ei;             // sources (x_j)
    const int* col = ei + N_EDGES;   // targets (aggregation index)

    char* ws = (char*)d_ws;
    size_t off = 0;
    float* dis = (float*)(ws + off); off += ((size_t)N_NODES * 4 + 255) & ~(size_t)255;
    float* buf0 = (float*)(ws + off); off += ((size_t)N_NODES * NCLASS * 4 + 255) & ~(size_t)255;  // 16 MB
    float* nrm = (float*)(ws + off); off += ((size_t)N_EDGES * 4 + 255) & ~(size_t)255;            // 6.4 MB
    float* outf = (float*)d_out;                                // N*40 floats = 16 MB

    const int B = 256;
    // degree / normalization
    deg_init<<<(N_NODES + B - 1) / B, B, 0, stream>>>(dis);
    deg_count<<<(N_EDGES + B - 1) / B, B, 0, stream>>>(col, dis);
    deg_to_dis<<<(N_NODES + B - 1) / B, B, 0, stream>>>(dis);
    prep_edges<<<(N_EDGES + B - 1) / B, B, 0, stream>>>(row, col, dis, nrm);

    // Z0 = X @ W  -> buf0
    gemm_xw<<<(N_NODES * NCLASS + B - 1) / B, B, 0, stream>>>(x, W, buf0);

    int grid_init = (N_NODES * 10 + B - 1) / B;
    int grid_edge = (N_EDGES * 10 + B - 1) / B;

    // hop 1: buf0 -> d_out
    hop_init<<<grid_init, B, 0, stream>>>(buf0, dis, nullptr, outf);
    hop_edges<<<grid_edge, B, 0, stream>>>(row, col, nrm, buf0, outf);
    // hop 2: d_out -> buf0
    hop_init<<<grid_init, B, 0, stream>>>(outf, dis, nullptr, buf0);
    hop_edges<<<grid_edge, B, 0, stream>>>(row, col, nrm, outf, buf0);
    // hop 3: buf0 -> d_out, + b folded into the self-loop term
    hop_init<<<grid_init, B, 0, stream>>>(buf0, dis, b, outf);
    hop_edges<<<grid_edge, B, 0, stream>>>(row, col, nrm, buf0, outf);
}

// Round 5
// 840.101 us; speedup vs baseline: 3.9215x; 3.9215x over previous
//
#include <hip/hip_runtime.h>

#define N_NODES 100000
#define N_EDGES 1600000
#define NFEAT 128
#define NCLASS 40
#define SCAN_T 1024

// ---------------- degree count (int) ----------------

__global__ void cnt_zero(int* __restrict__ cnt) {
    int i = blockIdx.x * blockDim.x + threadIdx.x;
    if (i < N_NODES) cnt[i] = 0;
}

__global__ void cnt_count(const int* __restrict__ col, int* __restrict__ cnt) {
    int e = blockIdx.x * blockDim.x + threadIdx.x;
    if (e < N_EDGES) atomicAdd(&cnt[col[e]], 1);
}

__global__ void dis_from_cnt(const int* __restrict__ cnt, float* __restrict__ dis) {
    int i = blockIdx.x * blockDim.x + threadIdx.x;
    if (i < N_NODES) dis[i] = rsqrtf((float)cnt[i] + 1.0f);  // +1 self-loop
}

// ---------------- single-block exclusive scan -> rowptr, cursor ----------------

__global__ __launch_bounds__(SCAN_T) void scan_rowptr(const int* __restrict__ cnt,
                                                      int* __restrict__ rowptr,
                                                      int* __restrict__ cursor) {
    __shared__ int sums[SCAN_T];
    int tid = threadIdx.x;
    const int chunk = (N_NODES + SCAN_T - 1) / SCAN_T;  // 98
    int beg = tid * chunk;
    int end = beg + chunk; if (end > N_NODES) end = N_NODES;
    int s = 0;
    for (int i = beg; i < end; ++i) s += cnt[i];
    sums[tid] = s;
    __syncthreads();
    // Hillis-Steele inclusive scan over 1024 partials
    for (int off = 1; off < SCAN_T; off <<= 1) {
        int v = sums[tid];
        int add = (tid >= off) ? sums[tid - off] : 0;
        __syncthreads();
        sums[tid] = v + add;
        __syncthreads();
    }
    int run = (tid == 0) ? 0 : sums[tid - 1];  // exclusive prefix of my chunk
    for (int i = beg; i < end; ++i) {
        rowptr[i] = run; cursor[i] = run;
        run += cnt[i];
    }
    if (tid == SCAN_T - 1) rowptr[N_NODES] = run;  // == N_EDGES
}

// ---------------- scatter edges into CSR: csr[slot] = {src, bitcast(norm)} ----------------

__global__ void scatter_csr(const int* __restrict__ row, const int* __restrict__ col,
                            const float* __restrict__ dis, int* __restrict__ cursor,
                            int2* __restrict__ csr) {
    int e = blockIdx.x * blockDim.x + threadIdx.x;
    if (e >= N_EDGES) return;
    int r = row[e];
    int c = col[e];
    int slot = atomicAdd(&cursor[c], 1);
    csr[slot] = make_int2(r, __float_as_int(dis[r] * dis[c]));
}

// ---------------- projection first: Z = X @ W  (N x 128 @ 128 x 40) ----------------

__global__ void gemm_xw(const float* __restrict__ x, const float* __restrict__ W,
                        float* __restrict__ z) {
    __shared__ float Ws[NFEAT * NCLASS];
    for (int i = threadIdx.x; i < NFEAT * NCLASS; i += blockDim.x) Ws[i] = W[i];
    __syncthreads();
    int t = blockIdx.x * blockDim.x + threadIdx.x;
    if (t >= N_NODES * NCLASS) return;
    int n = t / NCLASS;
    int c = t - n * NCLASS;
    const float* xr = x + (size_t)n * NFEAT;
    float acc = 0.0f;
#pragma unroll 8
    for (int f = 0; f < NFEAT; ++f) acc += xr[f] * Ws[f * NCLASS + c];
    z[t] = acc;
}

// ---------------- pull-mode hop: one wave per node, lanes 0..39 = feature cols ----------------

__global__ void hop_pull(const int* __restrict__ rowptr, const int2* __restrict__ csr,
                         const float* __restrict__ dis, const float* __restrict__ zin,
                         const float* __restrict__ b, float* __restrict__ zout) {
    int wid = (blockIdx.x * blockDim.x + threadIdx.x) >> 6;  // node
    int lane = threadIdx.x & 63;
    if (wid >= N_NODES) return;
    int beg = rowptr[wid];
    int end = rowptr[wid + 1];
    float d = dis[wid];
    float acc = 0.0f;
    if (lane < NCLASS) {
        acc = d * d * zin[wid * NCLASS + lane];  // self-loop term
        if (b != nullptr) acc += b[lane];
    }
    int k = beg;
    for (; k + 1 < end; k += 2) {  // 2-way unroll: two gathers in flight
        int2 p0 = csr[k];
        int2 p1 = csr[k + 1];
        float w0 = __int_as_float(p0.y);
        float w1 = __int_as_float(p1.y);
        if (lane < NCLASS) {
            float g0 = zin[p0.x * NCLASS + lane];
            float g1 = zin[p1.x * NCLASS + lane];
            acc += w0 * g0 + w1 * g1;
        }
    }
    if (k < end) {
        int2 p = csr[k];
        if (lane < NCLASS) acc += __int_as_float(p.y) * zin[p.x * NCLASS + lane];
    }
    if (lane < NCLASS) zout[wid * NCLASS + lane] = acc;
}

// ---------------- launch ----------------

extern "C" void kernel_launch(void* const* d_in, const int* in_sizes, int n_in,
                              void* d_out, int out_size, void* d_ws, size_t ws_size,
                              hipStream_t stream) {
    const float* x = (const float*)d_in[0];
    const int* ei = (const int*)d_in[1];   // int32 [2, E]
    const float* W = (const float*)d_in[2];
    const float* b = (const float*)d_in[3];
    // d_in[4] = k (fixed at 3 by setup)

    const int* row = ei;             // sources (x_j)
    const int* col = ei + N_EDGES;   // targets (aggregation index)

    char* ws = (char*)d_ws;
    size_t off = 0;
    auto alloc = [&](size_t bytes) { void* p = ws + off; off += (bytes + 255) & ~(size_t)255; return p; };
    int*   cnt    = (int*)  alloc((size_t)N_NODES * 4);
    float* dis    = (float*)alloc((size_t)N_NODES * 4);
    int*   rowptr = (int*)  alloc((size_t)(N_NODES + 1) * 4);
    int*   cursor = (int*)  alloc((size_t)N_NODES * 4);
    int2*  csr    = (int2*) alloc((size_t)N_EDGES * 8);            // 12.8 MB
    float* buf0   = (float*)alloc((size_t)N_NODES * NCLASS * 4);   // 16 MB
    float* outf   = (float*)d_out;

    const int B = 256;
    cnt_zero<<<(N_NODES + B - 1) / B, B, 0, stream>>>(cnt);
    cnt_count<<<(N_EDGES + B - 1) / B, B, 0, stream>>>(col, cnt);
    dis_from_cnt<<<(N_NODES + B - 1) / B, B, 0, stream>>>(cnt, dis);
    scan_rowptr<<<1, SCAN_T, 0, stream>>>(cnt, rowptr, cursor);
    scatter_csr<<<(N_EDGES + B - 1) / B, B, 0, stream>>>(row, col, dis, cursor, csr);

    // Z0 = X @ W -> buf0
    gemm_xw<<<(N_NODES * NCLASS + B - 1) / B, B, 0, stream>>>(x, W, buf0);

    int grid_hop = (int)(((size_t)N_NODES * 64 + B - 1) / B);  // one wave per node
    // hop 1: buf0 -> out
    hop_pull<<<grid_hop, B, 0, stream>>>(rowptr, csr, dis, buf0, nullptr, outf);
    // hop 2: out -> buf0
    hop_pull<<<grid_hop, B, 0, stream>>>(rowptr, csr, dis, outf, nullptr, buf0);
    // hop 3: buf0 -> out, + b
    hop_pull<<<grid_hop, B, 0, stream>>>(rowptr, csr, dis, buf0, b, outf);
}

// Round 9
// 537.806 us; speedup vs baseline: 6.1258x; 1.5621x over previous
//
#include <hip/hip_runtime.h>

#define N_NODES 100000
#define N_EDGES 1600000
#define NFEAT 128
#define NCLASS 40
#define SCAN_BLK 98   // ceil(100000 / 1024) blocks; 1024 nodes per block, 4 per thread

// ---------------- degree count (int) ----------------

__global__ void cnt_zero(int* __restrict__ cnt) {
    int i = blockIdx.x * blockDim.x + threadIdx.x;
    if (i < N_NODES) cnt[i] = 0;
}

__global__ void cnt_count(const int* __restrict__ col, int* __restrict__ cnt) {
    int e = blockIdx.x * blockDim.x + threadIdx.x;
    if (e < N_EDGES) atomicAdd(&cnt[col[e]], 1);
}

__global__ void dis_from_cnt(const int* __restrict__ cnt, float* __restrict__ dis) {
    int i = blockIdx.x * blockDim.x + threadIdx.x;
    if (i < N_NODES) dis[i] = rsqrtf((float)cnt[i] + 1.0f);  // +1 self-loop
}

// ---------------- two-level parallel scan -> rowptr, cursor ----------------

// A: per-block (1024 nodes) sums
__global__ void scan_partial(const int* __restrict__ cnt, int* __restrict__ bsum) {
    __shared__ int red[256];
    int blk = blockIdx.x, tid = threadIdx.x;
    int base = blk * 1024 + tid * 4;
    int s = 0;
    if (base + 3 < N_NODES) {
        int4 v = *reinterpret_cast<const int4*>(cnt + base);
        s = v.x + v.y + v.z + v.w;
    } else {
        for (int i = 0; i < 4; ++i) if (base + i < N_NODES) s += cnt[base + i];
    }
    red[tid] = s;
    __syncthreads();
    for (int o = 128; o > 0; o >>= 1) {
        if (tid < o) red[tid] += red[tid + o];
        __syncthreads();
    }
    if (tid == 0) bsum[blk] = red[0];
}

// B: scan the 98 partials (one tiny block), write exclusive bases in place
__global__ void scan_base(int* __restrict__ bsum, int* __restrict__ rowptr) {
    __shared__ int s[128];
    int tid = threadIdx.x;  // 128 threads
    s[tid] = (tid < SCAN_BLK) ? bsum[tid] : 0;
    __syncthreads();
    for (int o = 1; o < 128; o <<= 1) {
        int v = s[tid];
        int a = (tid >= o) ? s[tid - o] : 0;
        __syncthreads();
        s[tid] = v + a;
        __syncthreads();
    }
    if (tid < SCAN_BLK) bsum[tid] = (tid == 0) ? 0 : s[tid - 1];  // exclusive base
    if (tid == 0) rowptr[N_NODES] = s[SCAN_BLK - 1];              // total (= N_EDGES)
}

// C: per-block LDS scan + coalesced rowptr/cursor write
__global__ void scan_write(const int* __restrict__ cnt, const int* __restrict__ bsum,
                           int* __restrict__ rowptr, int* __restrict__ cursor) {
    __shared__ int psum[256];
    int blk = blockIdx.x, tid = threadIdx.x;
    int base = blk * 1024 + tid * 4;
    int c0 = 0, c1 = 0, c2 = 0, c3 = 0;
    if (base + 3 < N_NODES) {
        int4 v = *reinterpret_cast<const int4*>(cnt + base);
        c0 = v.x; c1 = v.y; c2 = v.z; c3 = v.w;
    } else {
        if (base < N_NODES)     c0 = cnt[base];
        if (base + 1 < N_NODES) c1 = cnt[base + 1];
        if (base + 2 < N_NODES) c2 = cnt[base + 2];
        if (base + 3 < N_NODES) c3 = cnt[base + 3];
    }
    int s = c0 + c1 + c2 + c3;
    psum[tid] = s;
    __syncthreads();
    for (int o = 1; o < 256; o <<= 1) {  // Hillis-Steele inclusive
        int v = psum[tid];
        int a = (tid >= o) ? psum[tid - o] : 0;
        __syncthreads();
        psum[tid] = v + a;
        __syncthreads();
    }
    int ex = psum[tid] - s + bsum[blk];  // exclusive prefix for this thread's 4 nodes
    if (base + 3 < N_NODES) {
        int4 rp = make_int4(ex, ex + c0, ex + c0 + c1, ex + c0 + c1 + c2);
        *reinterpret_cast<int4*>(rowptr + base) = rp;
        *reinterpret_cast<int4*>(cursor + base) = rp;
    } else {
        int r = ex;
        if (base < N_NODES)     { rowptr[base] = r;     cursor[base] = r;     r += c0; }
        if (base + 1 < N_NODES) { rowptr[base + 1] = r; cursor[base + 1] = r; r += c1; }
        if (base + 2 < N_NODES) { rowptr[base + 2] = r; cursor[base + 2] = r; r += c2; }
        if (base + 3 < N_NODES) { rowptr[base + 3] = r; cursor[base + 3] = r; }
    }
}

// ---------------- scatter edges into CSR: csr[slot] = {src, bitcast(norm)} ----------------

__global__ void scatter_csr(const int* __restrict__ row, const int* __restrict__ col,
                            const float* __restrict__ dis, int* __restrict__ cursor,
                            int2* __restrict__ csr) {
    int e = blockIdx.x * blockDim.x + threadIdx.x;
    if (e >= N_EDGES) return;
    int r = row[e];
    int c = col[e];
    int slot = atomicAdd(&cursor[c], 1);
    csr[slot] = make_int2(r, __float_as_int(dis[r] * dis[c]));
}

// ---------------- projection first: Z = X @ W  (N x 128 @ 128 x 40) ----------------

__global__ void gemm_xw(const float* __restrict__ x, const float* __restrict__ W,
                        float* __restrict__ z) {
    __shared__ float Ws[NFEAT * NCLASS];
    for (int i = threadIdx.x; i < NFEAT * NCLASS; i += blockDim.x) Ws[i] = W[i];
    __syncthreads();
    int t = blockIdx.x * blockDim.x + threadIdx.x;
    if (t >= N_NODES * NCLASS) return;
    int n = t / NCLASS;
    int c = t - n * NCLASS;
    const float* xr = x + (size_t)n * NFEAT;
    float acc = 0.0f;
#pragma unroll 8
    for (int f = 0; f < NFEAT; ++f) acc += xr[f] * Ws[f * NCLASS + c];
    z[t] = acc;
}

// ---------------- pull-mode hop: one wave per node, lanes 0..39 = feature cols ----------------

__global__ void hop_pull(const int* __restrict__ rowptr, const int2* __restrict__ csr,
                         const float* __restrict__ dis, const float* __restrict__ zin,
                         const float* __restrict__ b, float* __restrict__ zout) {
    int wid = (blockIdx.x * blockDim.x + threadIdx.x) >> 6;  // node
    int lane = threadIdx.x & 63;
    if (wid >= N_NODES) return;
    int beg = rowptr[wid];
    int end = rowptr[wid + 1];
    float d = dis[wid];
    float acc = 0.0f;
    if (lane < NCLASS) {
        acc = d * d * zin[wid * NCLASS + lane];  // self-loop term
        if (b != nullptr) acc += b[lane];
    }
    int k = beg;
    int n4 = beg + ((end - beg) & ~3);
    for (; k < n4; k += 4) {  // 4 independent gathers in flight
        int2 p0 = csr[k], p1 = csr[k + 1], p2 = csr[k + 2], p3 = csr[k + 3];
        if (lane < NCLASS) {
            float g0 = zin[p0.x * NCLASS + lane];
            float g1 = zin[p1.x * NCLASS + lane];
            float g2 = zin[p2.x * NCLASS + lane];
            float g3 = zin[p3.x * NCLASS + lane];
            acc += __int_as_float(p0.y) * g0 + __int_as_float(p1.y) * g1
                 + __int_as_float(p2.y) * g2 + __int_as_float(p3.y) * g3;
        }
    }
    for (; k < end; ++k) {
        int2 p = csr[k];
        if (lane < NCLASS) acc += __int_as_float(p.y) * zin[p.x * NCLASS + lane];
    }
    if (lane < NCLASS) zout[wid * NCLASS + lane] = acc;
}

// ---------------- launch ----------------

extern "C" void kernel_launch(void* const* d_in, const int* in_sizes, int n_in,
                              void* d_out, int out_size, void* d_ws, size_t ws_size,
                              hipStream_t stream) {
    const float* x = (const float*)d_in[0];
    const int* ei = (const int*)d_in[1];   // int32 [2, E]
    const float* W = (const float*)d_in[2];
    const float* b = (const float*)d_in[3];
    // d_in[4] = k (fixed at 3 by setup)

    const int* row = ei;             // sources (x_j)
    const int* col = ei + N_EDGES;   // targets (aggregation index)

    char* ws = (char*)d_ws;
    size_t off = 0;
    auto alloc = [&](size_t bytes) { void* p = ws + off; off += (bytes + 255) & ~(size_t)255; return p; };
    int*   cnt    = (int*)  alloc((size_t)N_NODES * 4);
    float* dis    = (float*)alloc((size_t)N_NODES * 4);
    int*   rowptr = (int*)  alloc((size_t)(N_NODES + 1) * 4);
    int*   cursor = (int*)  alloc((size_t)N_NODES * 4);
    int*   bsum   = (int*)  alloc(128 * 4);
    int2*  csr    = (int2*) alloc((size_t)N_EDGES * 8);            // 12.8 MB
    float* buf0   = (float*)alloc((size_t)N_NODES * NCLASS * 4);   // 16 MB
    float* outf   = (float*)d_out;

    const int B = 256;
    cnt_zero<<<(N_NODES + B - 1) / B, B, 0, stream>>>(cnt);
    cnt_count<<<(N_EDGES + B - 1) / B, B, 0, stream>>>(col, cnt);
    dis_from_cnt<<<(N_NODES + B - 1) / B, B, 0, stream>>>(cnt, dis);
    scan_partial<<<SCAN_BLK, 256, 0, stream>>>(cnt, bsum);
    scan_base<<<1, 128, 0, stream>>>(bsum, rowptr);
    scan_write<<<SCAN_BLK, 256, 0, stream>>>(cnt, bsum, rowptr, cursor);
    scatter_csr<<<(N_EDGES + B - 1) / B, B, 0, stream>>>(row, col, dis, cursor, csr);

    // Z0 = X @ W -> buf0
    gemm_xw<<<(N_NODES * NCLASS + B - 1) / B, B, 0, stream>>>(x, W, buf0);

    int grid_hop = (int)(((size_t)N_NODES * 64 + B - 1) / B);  // one wave per node
    // hop 1: buf0 -> out
    hop_pull<<<grid_hop, B, 0, stream>>>(rowptr, csr, dis, buf0, nullptr, outf);
    // hop 2: out -> buf0
    hop_pull<<<grid_hop, B, 0, stream>>>(rowptr, csr, dis, outf, nullptr, buf0);
    // hop 3: buf0 -> out, + b
    hop_pull<<<grid_hop, B, 0, stream>>>(rowptr, csr, dis, buf0, b, outf);
}

// Round 12
// 486.788 us; speedup vs baseline: 6.7678x; 1.1048x over previous
//
#include <hip/hip_runtime.h>

#define N_NODES 100000
#define N_EDGES 1600000
#define NFEAT 128
#define NCLASS 40
#define SCAN_BLK 98   // ceil(100000 / 1024) blocks; 1024 nodes per block, 4 per thread

// ---------------- degree count (int) ----------------

__global__ void cnt_zero(int* __restrict__ cnt) {
    int i = blockIdx.x * blockDim.x + threadIdx.x;
    if (i < N_NODES) cnt[i] = 0;
}

__global__ void cnt_count(const int* __restrict__ col, int* __restrict__ cnt) {
    int e = blockIdx.x * blockDim.x + threadIdx.x;
    if (e < N_EDGES) atomicAdd(&cnt[col[e]], 1);
}

__global__ void dis_from_cnt(const int* __restrict__ cnt, float* __restrict__ dis) {
    int i = blockIdx.x * blockDim.x + threadIdx.x;
    if (i < N_NODES) dis[i] = rsqrtf((float)cnt[i] + 1.0f);  // +1 self-loop
}

// ---------------- two-level parallel scan -> rowptr, cursor ----------------

// A: per-block (1024 nodes) sums
__global__ void scan_partial(const int* __restrict__ cnt, int* __restrict__ bsum) {
    __shared__ int red[256];
    int blk = blockIdx.x, tid = threadIdx.x;
    int base = blk * 1024 + tid * 4;
    int s = 0;
    if (base + 3 < N_NODES) {
        int4 v = *reinterpret_cast<const int4*>(cnt + base);
        s = v.x + v.y + v.z + v.w;
    } else {
        for (int i = 0; i < 4; ++i) if (base + i < N_NODES) s += cnt[base + i];
    }
    red[tid] = s;
    __syncthreads();
    for (int o = 128; o > 0; o >>= 1) {
        if (tid < o) red[tid] += red[tid + o];
        __syncthreads();
    }
    if (tid == 0) bsum[blk] = red[0];
}

// B: scan the 98 partials (one tiny block), write exclusive bases in place
__global__ void scan_base(int* __restrict__ bsum, int* __restrict__ rowptr) {
    __shared__ int s[128];
    int tid = threadIdx.x;  // 128 threads
    s[tid] = (tid < SCAN_BLK) ? bsum[tid] : 0;
    __syncthreads();
    for (int o = 1; o < 128; o <<= 1) {
        int v = s[tid];
        int a = (tid >= o) ? s[tid - o] : 0;
        __syncthreads();
        s[tid] = v + a;
        __syncthreads();
    }
    if (tid < SCAN_BLK) bsum[tid] = (tid == 0) ? 0 : s[tid - 1];  // exclusive base
    if (tid == 0) rowptr[N_NODES] = s[SCAN_BLK - 1];              // total (= N_EDGES)
}

// C: per-block LDS scan + coalesced rowptr/cursor write
__global__ void scan_write(const int* __restrict__ cnt, const int* __restrict__ bsum,
                           int* __restrict__ rowptr, int* __restrict__ cursor) {
    __shared__ int psum[256];
    int blk = blockIdx.x, tid = threadIdx.x;
    int base = blk * 1024 + tid * 4;
    int c0 = 0, c1 = 0, c2 = 0, c3 = 0;
    if (base + 3 < N_NODES) {
        int4 v = *reinterpret_cast<const int4*>(cnt + base);
        c0 = v.x; c1 = v.y; c2 = v.z; c3 = v.w;
    } else {
        if (base < N_NODES)     c0 = cnt[base];
        if (base + 1 < N_NODES) c1 = cnt[base + 1];
        if (base + 2 < N_NODES) c2 = cnt[base + 2];
        if (base + 3 < N_NODES) c3 = cnt[base + 3];
    }
    int s = c0 + c1 + c2 + c3;
    psum[tid] = s;
    __syncthreads();
    for (int o = 1; o < 256; o <<= 1) {  // Hillis-Steele inclusive
        int v = psum[tid];
        int a = (tid >= o) ? psum[tid - o] : 0;
        __syncthreads();
        psum[tid] = v + a;
        __syncthreads();
    }
    int ex = psum[tid] - s + bsum[blk];  // exclusive prefix for this thread's 4 nodes
    if (base + 3 < N_NODES) {
        int4 rp = make_int4(ex, ex + c0, ex + c0 + c1, ex + c0 + c1 + c2);
        *reinterpret_cast<int4*>(rowptr + base) = rp;
        *reinterpret_cast<int4*>(cursor + base) = rp;
    } else {
        int r = ex;
        if (base < N_NODES)     { rowptr[base] = r;     cursor[base] = r;     r += c0; }
        if (base + 1 < N_NODES) { rowptr[base + 1] = r; cursor[base + 1] = r; r += c1; }
        if (base + 2 < N_NODES) { rowptr[base + 2] = r; cursor[base + 2] = r; r += c2; }
        if (base + 3 < N_NODES) { rowptr[base + 3] = r; cursor[base + 3] = r; }
    }
}

// ---------------- scatter edges into CSR: csr[slot] = {src, bitcast(norm)} ----------------

__global__ void scatter_csr(const int* __restrict__ row, const int* __restrict__ col,
                            const float* __restrict__ dis, int* __restrict__ cursor,
                            int2* __restrict__ csr) {
    int e = blockIdx.x * blockDim.x + threadIdx.x;
    if (e >= N_EDGES) return;
    int r = row[e];
    int c = col[e];
    int slot = atomicAdd(&cursor[c], 1);
    csr[slot] = make_int2(r, __float_as_int(dis[r] * dis[c]));
}

// ---------------- projection first: Z = X @ W  (N x 128 @ 128 x 40) ----------------
// thread = node; 40 accs in registers; W via wave-uniform scalar loads (constant cache)

__global__ void gemm_xw(const float* __restrict__ x, const float* __restrict__ W,
                        float* __restrict__ z) {
    int n = blockIdx.x * blockDim.x + threadIdx.x;
    if (n >= N_NODES) return;
    const float4* xr = reinterpret_cast<const float4*>(x + (size_t)n * NFEAT);
    float acc[NCLASS];
#pragma unroll
    for (int c = 0; c < NCLASS; ++c) acc[c] = 0.0f;
    for (int fb = 0; fb < NFEAT / 4; ++fb) {
        float4 xv = xr[fb];
#pragma unroll
        for (int j = 0; j < 4; ++j) {
            float xs = (&xv.x)[j];
            const float* wrow = W + (fb * 4 + j) * NCLASS;  // wave-uniform -> s_load
#pragma unroll
            for (int c = 0; c < NCLASS; ++c) acc[c] += xs * wrow[c];
        }
    }
    float4* zr = reinterpret_cast<float4*>(z + (size_t)n * NCLASS);
#pragma unroll
    for (int cb = 0; cb < NCLASS / 4; ++cb)
        zr[cb] = make_float4(acc[cb * 4], acc[cb * 4 + 1], acc[cb * 4 + 2], acc[cb * 4 + 3]);
}

// ---------------- pull-mode hop: one wave per node, lanes 0..39 = feature cols ----------------

__global__ void hop_pull(const int* __restrict__ rowptr, const int2* __restrict__ csr,
                         const float* __restrict__ dis, const float* __restrict__ zin,
                         const float* __restrict__ b, float* __restrict__ zout) {
    int wid = (blockIdx.x * blockDim.x + threadIdx.x) >> 6;  // node
    int lane = threadIdx.x & 63;
    if (wid >= N_NODES) return;
    int beg = rowptr[wid];
    int end = rowptr[wid + 1];
    float d = dis[wid];
    float acc = 0.0f;
    if (lane < NCLASS) {
        acc = d * d * zin[wid * NCLASS + lane];  // self-loop term
        if (b != nullptr) acc += b[lane];
    }
    int k = beg;
    int n4 = beg + ((end - beg) & ~3);
    for (; k < n4; k += 4) {  // 4 independent gathers in flight
        int2 p0 = csr[k], p1 = csr[k + 1], p2 = csr[k + 2], p3 = csr[k + 3];
        if (lane < NCLASS) {
            float g0 = zin[p0.x * NCLASS + lane];
            float g1 = zin[p1.x * NCLASS + lane];
            float g2 = zin[p2.x * NCLASS + lane];
            float g3 = zin[p3.x * NCLASS + lane];
            acc += __int_as_float(p0.y) * g0 + __int_as_float(p1.y) * g1
                 + __int_as_float(p2.y) * g2 + __int_as_float(p3.y) * g3;
        }
    }
    for (; k < end; ++k) {
        int2 p = csr[k];
        if (lane < NCLASS) acc += __int_as_float(p.y) * zin[p.x * NCLASS + lane];
    }
    if (lane < NCLASS) zout[wid * NCLASS + lane] = acc;
}

// ---------------- launch ----------------

extern "C" void kernel_launch(void* const* d_in, const int* in_sizes, int n_in,
                              void* d_out, int out_size, void* d_ws, size_t ws_size,
                              hipStream_t stream) {
    const float* x = (const float*)d_in[0];
    const int* ei = (const int*)d_in[1];   // int32 [2, E]
    const float* W = (const float*)d_in[2];
    const float* b = (const float*)d_in[3];
    // d_in[4] = k (fixed at 3 by setup)

    const int* row = ei;             // sources (x_j)
    const int* col = ei + N_EDGES;   // targets (aggregation index)

    char* ws = (char*)d_ws;
    size_t off = 0;
    auto alloc = [&](size_t bytes) { void* p = ws + off; off += (bytes + 255) & ~(size_t)255; return p; };
    int*   cnt    = (int*)  alloc((size_t)N_NODES * 4);
    float* dis    = (float*)alloc((size_t)N_NODES * 4);
    int*   rowptr = (int*)  alloc((size_t)(N_NODES + 1) * 4);
    int*   cursor = (int*)  alloc((size_t)N_NODES * 4);
    int*   bsum   = (int*)  alloc(128 * 4);
    int2*  csr    = (int2*) alloc((size_t)N_EDGES * 8);            // 12.8 MB
    float* buf0   = (float*)alloc((size_t)N_NODES * NCLASS * 4);   // 16 MB
    float* outf   = (float*)d_out;

    const int B = 256;
    cnt_zero<<<(N_NODES + B - 1) / B, B, 0, stream>>>(cnt);
    cnt_count<<<(N_EDGES + B - 1) / B, B, 0, stream>>>(col, cnt);
    dis_from_cnt<<<(N_NODES + B - 1) / B, B, 0, stream>>>(cnt, dis);
    scan_partial<<<SCAN_BLK, 256, 0, stream>>>(cnt, bsum);
    scan_base<<<1, 128, 0, stream>>>(bsum, rowptr);
    scan_write<<<SCAN_BLK, 256, 0, stream>>>(cnt, bsum, rowptr, cursor);
    scatter_csr<<<(N_EDGES + B - 1) / B, B, 0, stream>>>(row, col, dis, cursor, csr);

    // Z0 = X @ W -> buf0  (thread per node)
    gemm_xw<<<(N_NODES + B - 1) / B, B, 0, stream>>>(x, W, buf0);

    int grid_hop = (int)(((size_t)N_NODES * 64 + B - 1) / B);  // one wave per node
    // hop 1: buf0 -> out
    hop_pull<<<grid_hop, B, 0, stream>>>(rowptr, csr, dis, buf0, nullptr, outf);
    // hop 2: out -> buf0
    hop_pull<<<grid_hop, B, 0, stream>>>(rowptr, csr, dis, outf, nullptr, buf0);
    // hop 3: buf0 -> out, + b
    hop_pull<<<grid_hop, B, 0, stream>>>(rowptr, csr, dis, buf0, b, outf);
}